// Round 5
// baseline (289.311 us; speedup 1.0000x reference)
//
#include <hip/hip_runtime.h>

#define NT    8192      // tokens (B*S)
#define DIM   1024      // d_model
#define NE    8         // experts
#define NH    512       // hidden
#define NROWS (NT*2)    // token-expert assignments (top_k=2)

typedef _Float16 f16;
typedef unsigned int u32;
typedef __attribute__((ext_vector_type(8))) _Float16 f16x8;
typedef __attribute__((ext_vector_type(4))) _Float16 f16x4;
typedef __attribute__((ext_vector_type(2))) _Float16 f16x2;
typedef __attribute__((ext_vector_type(4))) float f32x4;

// global -> LDS direct DMA, 16B per lane (wave-uniform base + lane*16).
__device__ __forceinline__ void gl2lds16(const f16* gptr, f16* ldsptr) {
    __builtin_amdgcn_global_load_lds(
        (const __attribute__((address_space(1))) u32*)gptr,
        (__attribute__((address_space(3))) u32*)ldsptr, 16, 0, 0);
}

// XOR-swizzled fragment read from unpadded [rows][32] f16 sub-tile
// (proven conflict-free: SQ_LDS_BANK_CONFLICT == 0).
#define FR(sbuf, row, q) \
    (*(const f16x8*)&sbuf[(row)*32 + (((q) ^ (((row) >> 1) & 3)) << 3)])

// ---------------- prep: out=0 + router logits + x->f16 + weight transpose ---
#define KC 512
__global__ __launch_bounds__(256) void prep_kernel(
    const float* __restrict__ x, const float* __restrict__ wr,
    const float* __restrict__ w1, const float* __restrict__ w3,
    const float* __restrict__ w2, float* __restrict__ plogits,
    f16* __restrict__ x16,
    f16* __restrict__ w1t, f16* __restrict__ w3t, f16* __restrict__ w2t,
    int* __restrict__ zint, float* __restrict__ out)
{
    __shared__ float smem[NE*KC];   // 16 KiB; transpose uses all 64*64 floats
    int tid = threadIdx.x;
    int bi = blockIdx.x;
    // zero out (gemm2 accumulates into it with atomics). 8KB per block.
    {
        float4 z = {0.f, 0.f, 0.f, 0.f};
        float4* op = (float4*)out + (size_t)bi*512 + tid;
        op[0] = z;
        op[256] = z;
    }
    if (bi == 0 && tid < 16) zint[tid] = 0;   // ghist[8] | gcur[8]
    if (bi < 1024) {
        int bx = bi & 511, by = bi >> 9;
        int kc0 = by * KC;
        for (int i = tid; i < NE*KC; i += 256) {
            int k = i >> 3, e = i & 7;
            smem[e*KC + k] = wr[(size_t)kc0*NE + i];
        }
        __syncthreads();
        int tok = bx*16 + (tid >> 4);
        int kl  = tid & 15;
        float acc[NE];
        #pragma unroll
        for (int e = 0; e < NE; e++) acc[e] = 0.f;
        const float* xrow = x + (size_t)tok*DIM + kc0;
        f16* xhrow = x16 + (size_t)tok*DIM + kc0;
        #pragma unroll
        for (int i = 0; i < KC/64; i++) {
            int kb = i*64 + kl*4;
            float4 xv = *(const float4*)(xrow + kb);
            f16x4 xh = { (f16)xv.x, (f16)xv.y, (f16)xv.z, (f16)xv.w };
            *(f16x4*)(xhrow + kb) = xh;
            #pragma unroll
            for (int e = 0; e < NE; e++) {
                float4 wv = *(const float4*)&smem[e*KC + kb];
                acc[e] += xv.x*wv.x + xv.y*wv.y + xv.z*wv.z + xv.w*wv.w;
            }
        }
        #pragma unroll
        for (int e = 0; e < NE; e++) {
            float v = acc[e];
            v += __shfl_xor(v, 1); v += __shfl_xor(v, 2);
            v += __shfl_xor(v, 4); v += __shfl_xor(v, 8);
            acc[e] = v;
        }
        if (kl == 0) {
            float* pp = plogits + ((size_t)by*NT + tok)*NE;
            float4 o0 = {acc[0], acc[1], acc[2], acc[3]};
            float4 o1 = {acc[4], acc[5], acc[6], acc[7]};
            *(float4*)pp = o0;
            *(float4*)(pp + 4) = o1;
        }
    } else {
        int tz = bi - 1024;
        int zx = tz & 127, zy = tz >> 7;      // 128 64x64 tiles per (tensor,e)
        int tensor = zy >> 3, e = zy & 7;
        const float* src; f16* dst; int R, C;
        if (tensor == 0)      { src = w1; dst = w1t; R = DIM; C = NH; }
        else if (tensor == 1) { src = w3; dst = w3t; R = DIM; C = NH; }
        else                  { src = w2; dst = w2t; R = NH; C = DIM; }
        src += (size_t)e * DIM * NH;
        dst += (size_t)e * DIM * NH;
        int tcols = C >> 6;
        int bx = zx % tcols, by = zx / tcols;
        int r0 = by*64, c0 = bx*64;
        #pragma unroll
        for (int p = 0; p < 4; p++) {
            int r = p*16 + (tid >> 4);
            int c = (tid & 15) << 2;
            float4 v = *(const float4*)&src[(size_t)(r0 + r)*C + c0 + c];
            *(float4*)&smem[r*64 + (c ^ (((r >> 3) & 7) << 2))] = v;
        }
        __syncthreads();
        #pragma unroll
        for (int pass = 0; pass < 2; pass++) {
            int s = pass*256 + tid;
            int h = s >> 3, a = s & 7, d0 = a << 3;
            int hs = h ^ (a << 2);
            f16x8 o;
            #pragma unroll
            for (int j = 0; j < 8; j++)
                o[j] = (f16)smem[(d0 + j)*64 + hs];
            *(f16x8*)&dst[(size_t)(c0 + h)*R + r0 + d0] = o;
        }
    }
}

// ---------------- route: softmax+top2 per token + global histogram ----------
__global__ __launch_bounds__(256) void route_kernel(
    const float* __restrict__ plogits, unsigned char* __restrict__ ge,
    float* __restrict__ gw, int* __restrict__ zint)
{
    __shared__ int lhist[NE];
    int tid = threadIdx.x;
    if (tid < NE) lhist[tid] = 0;
    __syncthreads();

    int t = blockIdx.x*256 + tid;
    const float* p0 = plogits + (size_t)t*NE;
    const float* p1 = plogits + (size_t)NT*NE + (size_t)t*NE;
    float4 a0 = *(const float4*)p0, a1 = *(const float4*)(p0+4);
    float4 b0 = *(const float4*)p1, b1 = *(const float4*)(p1+4);
    float l[NE] = { a0.x+b0.x, a0.y+b0.y, a0.z+b0.z, a0.w+b0.w,
                    a1.x+b1.x, a1.y+b1.y, a1.z+b1.z, a1.w+b1.w };
    float m = l[0];
    #pragma unroll
    for (int e = 1; e < NE; e++) m = fmaxf(m, l[e]);
    float s = 0.f;
    #pragma unroll
    for (int e = 0; e < NE; e++) { l[e] = __expf(l[e] - m); s += l[e]; }
    float inv = 1.f / s;
    int i0 = 0; float v0 = l[0];
    #pragma unroll
    for (int e = 1; e < NE; e++) if (l[e] > v0) { v0 = l[e]; i0 = e; }
    int i1 = -1; float v1 = -1.f;
    #pragma unroll
    for (int e = 0; e < NE; e++) if (e != i0 && l[e] > v1) { v1 = l[e]; i1 = e; }
    ge[2*t+0] = (unsigned char)i0; gw[2*t+0] = v0*inv;
    ge[2*t+1] = (unsigned char)i1; gw[2*t+1] = v1*inv;
    #pragma unroll
    for (int ee = 0; ee < NE; ee++) {
        int c = __popcll(__ballot(i0 == ee)) + __popcll(__ballot(i1 == ee));
        if ((tid & 63) == 0 && c) atomicAdd(&lhist[ee], c);
    }
    __syncthreads();
    if (tid < NE && lhist[tid]) atomicAdd(&zint[tid], lhist[tid]);   // ghist
}

// ---------------- scatter: ranked compaction via device-scope atomics -------
__global__ __launch_bounds__(256) void scatter_kernel(
    const unsigned char* __restrict__ ge, const float* __restrict__ gw,
    int* __restrict__ zint, int* __restrict__ offs, int* __restrict__ tok_ids,
    int* __restrict__ aid, float* __restrict__ row_gate)
{
    const int* ghist = zint;
    int* gcur = zint + 8;
    int tid = threadIdx.x;
    int loffs[NE]; int s = 0;
    #pragma unroll
    for (int e = 0; e < NE; e++) { loffs[e] = s; s += ghist[e]; }
    if (blockIdx.x == 0 && tid == 0) {
        #pragma unroll
        for (int e = 0; e < NE; e++) offs[e] = loffs[e];
        offs[NE] = s;
    }
    int id = blockIdx.x*256 + tid;
    int e = ge[id];
    float wv = gw[id];
    unsigned long long lt = (1ULL << (tid & 63)) - 1;
    int pos = 0;
    #pragma unroll
    for (int ee = 0; ee < NE; ee++) {
        unsigned long long mk = __ballot(e == ee);
        int cnt = __popcll(mk);
        int b = 0;
        if ((tid & 63) == 0 && cnt) b = atomicAdd(&gcur[ee], cnt);
        b = __shfl(b, 0);
        if (e == ee) pos = loffs[ee] + b + __popcll(mk & lt);
    }
    tok_ids[pos] = id >> 1;
    aid[pos] = id;
    row_gate[pos] = wv;
}

// ---------------- grouped GEMM tiles ----------------
// All GEMMs: 128x128 tile, BK=64 as two 32-wide sub-tiles, full-drain
// schedule, full DMA staging (the proven gemm2 structure).

// GEMM1a: s1buf = silu(x16 @ w1t) for expert-sorted rows.
#define BM1 128
#define BN1 128
__global__ __launch_bounds__(256,3) void gemm1a_kernel(
    const f16* __restrict__ x16, const int* __restrict__ tok_ids,
    const f16* __restrict__ w1t, f16* __restrict__ s1buf,
    const int* __restrict__ offs)
{
    int bi = blockIdx.x;
    int e  = bi & 7;
    int r_ = bi >> 3;
    int nt = r_ & 3;          // NH/BN1 = 4
    int mt = r_ >> 2;
    int off = offs[e];
    int n_e = offs[e+1] - off;
    if (mt*BM1 >= n_e) return;

    __shared__ f16 sA[2][BM1*32];   // 16 KB
    __shared__ f16 sB[2][BN1*32];   // 16 KB
    __shared__ int stok[BM1];

    int tid = threadIdx.x;
    if (tid < BM1) {
        int rloc = mt*BM1 + tid; rloc = rloc < n_e ? rloc : n_e - 1;
        stok[tid] = tok_ids[off + rloc];
    }
    __syncthreads();

    int lane = tid & 63, w = tid >> 6;
    int wrow = (w >> 1)*64, wcol = (w & 1)*64;
    int q = lane >> 4, lm = lane & 15;

    int lr0 = w*32 + (lane >> 2);
    int lr1 = lr0 + 16;
    int g0 = (lane & 3) ^ ((lr0 >> 1) & 3);
    int g1 = (lane & 3) ^ ((lr1 >> 1) & 3);
    const f16* pA0 = x16 + (size_t)stok[lr0]*DIM + g0*8;
    const f16* pA1 = x16 + (size_t)stok[lr1]*DIM + g1*8;
    const f16* wp  = w1t + ((size_t)e*NH + nt*BN1)*DIM;
    const f16* pB0 = wp + (size_t)lr0*DIM + g0*8;
    const f16* pB1 = wp + (size_t)lr1*DIM + g1*8;
    const int l0 = lr0*32 + ((lane & 3) << 3);
    const int l1 = lr1*32 + ((lane & 3) << 3);

    f32x4 acc[4][4];
    #pragma unroll
    for (int a = 0; a < 4; a++)
        #pragma unroll
        for (int b = 0; b < 4; b++) acc[a][b] = (f32x4){0.f,0.f,0.f,0.f};

    for (int k0 = 0; k0 < DIM; k0 += 64) {
        gl2lds16(pA0 + k0,      &sA[0][l0]);
        gl2lds16(pA1 + k0,      &sA[0][l1]);
        gl2lds16(pA0 + k0 + 32, &sA[1][l0]);
        gl2lds16(pA1 + k0 + 32, &sA[1][l1]);
        gl2lds16(pB0 + k0,      &sB[0][l0]);
        gl2lds16(pB1 + k0,      &sB[0][l1]);
        gl2lds16(pB0 + k0 + 32, &sB[1][l0]);
        gl2lds16(pB1 + k0 + 32, &sB[1][l1]);
        __syncthreads();   // drains DMA
        #pragma unroll
        for (int ks = 0; ks < 2; ks++) {
            f16x8 aF[4], bF[4];
            #pragma unroll
            for (int s = 0; s < 4; s++) {
                aF[s] = FR(sA[ks], wrow + s*16 + lm, q);
                bF[s] = FR(sB[ks], wcol + s*16 + lm, q);
            }
            #pragma unroll
            for (int sr = 0; sr < 4; sr++)
                #pragma unroll
                for (int sc = 0; sc < 4; sc++)
                    acc[sr][sc] = __builtin_amdgcn_mfma_f32_16x16x32_f16(aF[sr], bF[sc], acc[sr][sc], 0, 0, 0);
        }
        __syncthreads();   // reads done before next iter's DMA
    }
    // epilogue: silu(h1) -> f16 s1buf
    #pragma unroll
    for (int sr = 0; sr < 4; sr++) {
        #pragma unroll
        for (int reg = 0; reg < 4; reg++) {
            int row = mt*BM1 + wrow + sr*16 + q*4 + reg;
            if (row < n_e) {
                #pragma unroll
                for (int sc = 0; sc < 4; sc++) {
                    int col = nt*BN1 + wcol + sc*16 + lm;
                    float h1 = acc[sr][sc][reg];
                    s1buf[(size_t)(off + row)*NH + col] = (f16)(h1 / (1.f + __expf(-h1)));
                }
            }
        }
    }
}

// GEMM1b: gbuf = s1buf * (x16 @ w3t).
__global__ __launch_bounds__(256,3) void gemm1b_kernel(
    const f16* __restrict__ x16, const int* __restrict__ tok_ids,
    const f16* __restrict__ w3t, const f16* __restrict__ s1buf,
    f16* __restrict__ gbuf, const int* __restrict__ offs)
{
    int bi = blockIdx.x;
    int e  = bi & 7;
    int r_ = bi >> 3;
    int nt = r_ & 3;          // NH/BN1 = 4
    int mt = r_ >> 2;
    int off = offs[e];
    int n_e = offs[e+1] - off;
    if (mt*BM1 >= n_e) return;

    __shared__ f16 sA[2][BM1*32];   // 16 KB
    __shared__ f16 sB[2][BN1*32];   // 16 KB
    __shared__ int stok[BM1];

    int tid = threadIdx.x;
    if (tid < BM1) {
        int rloc = mt*BM1 + tid; rloc = rloc < n_e ? rloc : n_e - 1;
        stok[tid] = tok_ids[off + rloc];
    }
    __syncthreads();

    int lane = tid & 63, w = tid >> 6;
    int wrow = (w >> 1)*64, wcol = (w & 1)*64;
    int q = lane >> 4, lm = lane & 15;

    int lr0 = w*32 + (lane >> 2);
    int lr1 = lr0 + 16;
    int g0 = (lane & 3) ^ ((lr0 >> 1) & 3);
    int g1 = (lane & 3) ^ ((lr1 >> 1) & 3);
    const f16* pA0 = x16 + (size_t)stok[lr0]*DIM + g0*8;
    const f16* pA1 = x16 + (size_t)stok[lr1]*DIM + g1*8;
    const f16* wp  = w3t + ((size_t)e*NH + nt*BN1)*DIM;
    const f16* pB0 = wp + (size_t)lr0*DIM + g0*8;
    const f16* pB1 = wp + (size_t)lr1*DIM + g1*8;
    const int l0 = lr0*32 + ((lane & 3) << 3);
    const int l1 = lr1*32 + ((lane & 3) << 3);

    f32x4 acc[4][4];
    #pragma unroll
    for (int a = 0; a < 4; a++)
        #pragma unroll
        for (int b = 0; b < 4; b++) acc[a][b] = (f32x4){0.f,0.f,0.f,0.f};

    for (int k0 = 0; k0 < DIM; k0 += 64) {
        gl2lds16(pA0 + k0,      &sA[0][l0]);
        gl2lds16(pA1 + k0,      &sA[0][l1]);
        gl2lds16(pA0 + k0 + 32, &sA[1][l0]);
        gl2lds16(pA1 + k0 + 32, &sA[1][l1]);
        gl2lds16(pB0 + k0,      &sB[0][l0]);
        gl2lds16(pB1 + k0,      &sB[0][l1]);
        gl2lds16(pB0 + k0 + 32, &sB[1][l0]);
        gl2lds16(pB1 + k0 + 32, &sB[1][l1]);
        __syncthreads();   // drains DMA
        #pragma unroll
        for (int ks = 0; ks < 2; ks++) {
            f16x8 aF[4], bF[4];
            #pragma unroll
            for (int s = 0; s < 4; s++) {
                aF[s] = FR(sA[ks], wrow + s*16 + lm, q);
                bF[s] = FR(sB[ks], wcol + s*16 + lm, q);
            }
            #pragma unroll
            for (int sr = 0; sr < 4; sr++)
                #pragma unroll
                for (int sc = 0; sc < 4; sc++)
                    acc[sr][sc] = __builtin_amdgcn_mfma_f32_16x16x32_f16(aF[sr], bF[sc], acc[sr][sc], 0, 0, 0);
        }
        __syncthreads();   // reads done before next iter's DMA
    }
    // epilogue: g = s1 * h3 -> f16 gbuf
    #pragma unroll
    for (int sr = 0; sr < 4; sr++) {
        #pragma unroll
        for (int reg = 0; reg < 4; reg++) {
            int row = mt*BM1 + wrow + sr*16 + q*4 + reg;
            if (row < n_e) {
                #pragma unroll
                for (int sc = 0; sc < 4; sc++) {
                    int col = nt*BN1 + wcol + sc*16 + lm;
                    float s1 = (float)s1buf[(size_t)(off + row)*NH + col];
                    float gv = s1 * acc[sr][sc][reg];
                    gbuf[(size_t)(off + row)*NH + col] = (f16)gv;
                }
            }
        }
    }
}

// GEMM2: out[t] += gate * (G @ W2) via fp32 atomics (exactly 2 adds/element,
// commutative -> deterministic). combine kernel eliminated.
#define BM 128
#define BN 128
__global__ __launch_bounds__(256,3) void gemm2_kernel(
    const f16* __restrict__ gbuf, const f16* __restrict__ w2t,
    const int* __restrict__ offs, const int* __restrict__ aid,
    const float* __restrict__ row_gate, float* __restrict__ out)
{
    int bi = blockIdx.x;
    int e  = bi & 7;
    int r_ = bi >> 3;
    int nt = r_ & 7;          // DIM/BN = 8
    int mt = r_ >> 3;
    int off = offs[e];
    int n_e = offs[e+1] - off;
    if (mt*BM >= n_e) return;

    __shared__ f16 sA[2][BM*32];   // 16 KB
    __shared__ f16 sB[2][BN*32];   // 16 KB
    __shared__ int said[BM];
    __shared__ float sgate[BM];

    int tid = threadIdx.x;
    if (tid < BM) {
        int rloc = mt*BM + tid;
        if (rloc < n_e) { said[tid] = aid[off + rloc]; sgate[tid] = row_gate[off + rloc]; }
        else            { said[tid] = 0; sgate[tid] = 0.f; }
    }

    int lane = tid & 63, w = tid >> 6;
    int wrow = (w >> 1)*64, wcol = (w & 1)*64;
    int q = lane >> 4, lm = lane & 15;

    int lr0 = w*32 + (lane >> 2);
    int lr1 = lr0 + 16;
    int g0 = (lane & 3) ^ ((lr0 >> 1) & 3);
    int g1 = (lane & 3) ^ ((lr1 >> 1) & 3);
    int ga0 = mt*BM + lr0; ga0 = ga0 < n_e ? ga0 : n_e - 1;
    int ga1 = mt*BM + lr1; ga1 = ga1 < n_e ? ga1 : n_e - 1;
    const f16* pA0 = gbuf + (size_t)(off + ga0)*NH + g0*8;
    const f16* pA1 = gbuf + (size_t)(off + ga1)*NH + g1*8;
    const f16* w2p = w2t + ((size_t)e*DIM + nt*BN)*NH;
    const f16* pB0 = w2p + (size_t)lr0*NH + g0*8;
    const f16* pB1 = w2p + (size_t)lr1*NH + g1*8;
    const int lofs0 = lr0*32 + ((lane & 3) << 3);
    const int lofs1 = lr1*32 + ((lane & 3) << 3);

    f32x4 acc[4][4];
    #pragma unroll
    for (int a = 0; a < 4; a++)
        #pragma unroll
        for (int b = 0; b < 4; b++) acc[a][b] = (f32x4){0.f,0.f,0.f,0.f};

    __syncthreads();   // covers said/sgate writes

    for (int k0 = 0; k0 < NH; k0 += 64) {
        gl2lds16(pA0 + k0,      &sA[0][lofs0]);
        gl2lds16(pA1 + k0,      &sA[0][lofs1]);
        gl2lds16(pA0 + k0 + 32, &sA[1][lofs0]);
        gl2lds16(pA1 + k0 + 32, &sA[1][lofs1]);
        gl2lds16(pB0 + k0,      &sB[0][lofs0]);
        gl2lds16(pB1 + k0,      &sB[0][lofs1]);
        gl2lds16(pB0 + k0 + 32, &sB[1][lofs0]);
        gl2lds16(pB1 + k0 + 32, &sB[1][lofs1]);
        __syncthreads();   // drains vmcnt
        #pragma unroll
        for (int ks = 0; ks < 2; ks++) {
            f16x8 aF[4], bF[4];
            #pragma unroll
            for (int s = 0; s < 4; s++) {
                aF[s] = FR(sA[ks], wrow + s*16 + lm, q);
                bF[s] = FR(sB[ks], wcol + s*16 + lm, q);
            }
            #pragma unroll
            for (int sr = 0; sr < 4; sr++)
                #pragma unroll
                for (int sc = 0; sc < 4; sc++)
                    acc[sr][sc] = __builtin_amdgcn_mfma_f32_16x16x32_f16(aF[sr], bF[sc], acc[sr][sc], 0, 0, 0);
        }
        __syncthreads();   // reads done before next iter's DMA
    }
    #pragma unroll
    for (int sr = 0; sr < 4; sr++) {
        #pragma unroll
        for (int reg = 0; reg < 4; reg++) {
            int lrow = wrow + sr*16 + q*4 + reg;
            if (mt*BM + lrow < n_e) {
                int id = said[lrow];
                float wgt = sgate[lrow];
                #pragma unroll
                for (int sc = 0; sc < 4; sc++) {
                    int col = nt*BN + wcol + sc*16 + lm;
                    float v = (float)(f16)(wgt * acc[sr][sc][reg]);
                    atomicAdd(&out[(size_t)(id >> 1)*DIM + col], v);
                }
            }
        }
    }
}

extern "C" void kernel_launch(void* const* d_in, const int* in_sizes, int n_in,
                              void* d_out, int out_size, void* d_ws, size_t ws_size,
                              hipStream_t stream)
{
    const float* x  = (const float*)d_in[0];
    const float* wr = (const float*)d_in[1];
    const float* w1 = (const float*)d_in[2];
    const float* w2 = (const float*)d_in[3];
    const float* w3 = (const float*)d_in[4];
    float* out = (float*)d_out;

    char* ws = (char*)d_ws;
    f16* scratch = (f16*)ws;        ws += (size_t)NROWS*DIM*sizeof(f16);   // 32 MiB: x16 (16) + s1buf (16)
    f16* w1t     = (f16*)ws;        ws += (size_t)NE*NH*DIM*sizeof(f16);   // 8 MiB (writer: prep)
    f16* w3t     = (f16*)ws;        ws += (size_t)NE*NH*DIM*sizeof(f16);   // 8 MiB (writer: prep)
    f16* w2t     = (f16*)ws;        ws += (size_t)NE*DIM*NH*sizeof(f16);   // 8 MiB (writer: prep)
    f16* gbuf    = (f16*)ws;        ws += (size_t)NROWS*NH*sizeof(f16);    // 16 MiB (writer: gemm1b)
    float* plogits = (float*)ws;    ws += (size_t)2*NT*NE*4;               // 512 KiB (writer: prep)
    int* tok_ids = (int*)ws;        ws += (size_t)NROWS*4;                 // (writer: scatter)
    int* aid     = (int*)ws;        ws += (size_t)NROWS*4;
    float* row_gate = (float*)ws;   ws += (size_t)NROWS*4;
    int* offs    = (int*)ws;        ws += 64;
    unsigned char* ge = (unsigned char*)ws; ws += (size_t)NROWS;           // (writer: route)
    float* gw    = (float*)ws;      ws += (size_t)NROWS*4;
    int* zint    = (int*)ws;        ws += 64;                              // ghist[8]|gcur[8]
    if (ws_size < (size_t)(ws - (char*)d_ws)) return;  // ~72.8 MB needed

    // scratch region reuse: x16 (first 16 MiB, writer prep) + s1buf (second
    // 16 MiB, writer gemm1a). Both dead after gemm1b.
    f16* x16   = scratch;
    f16* s1buf = scratch + (size_t)NT*DIM;

    prep_kernel<<<1024 + 3072, 256, 0, stream>>>(x, wr, w1, w3, w2,
                                                 plogits, x16, w1t, w3t, w2t,
                                                 zint, out);
    route_kernel<<<NT/256, 256, 0, stream>>>(plogits, ge, gw, zint);
    scatter_kernel<<<NROWS/256, 256, 0, stream>>>(ge, gw, zint, offs,
                                                  tok_ids, aid, row_gate);
    gemm1a_kernel<<<4096, 256, 0, stream>>>(x16, tok_ids, w1t, s1buf, offs);
    gemm1b_kernel<<<4096, 256, 0, stream>>>(x16, tok_ids, w3t, s1buf, gbuf, offs);
    gemm2_kernel<<<8192, 256, 0, stream>>>(gbuf, w2t, offs, aid, row_gate, out);
}

// Round 6
// 258.735 us; speedup vs baseline: 1.1182x; 1.1182x over previous
//
#include <hip/hip_runtime.h>

#define NT    8192      // tokens (B*S)
#define DIM   1024      // d_model
#define NE    8         // experts
#define NH    512       // hidden
#define NROWS (NT*2)    // token-expert assignments (top_k=2)

typedef _Float16 f16;
typedef unsigned int u32;
typedef __attribute__((ext_vector_type(8))) _Float16 f16x8;
typedef __attribute__((ext_vector_type(4))) _Float16 f16x4;
typedef __attribute__((ext_vector_type(2))) _Float16 f16x2;
typedef __attribute__((ext_vector_type(4))) float f32x4;

// global -> LDS direct DMA, 16B per lane (wave-uniform base + lane*16).
__device__ __forceinline__ void gl2lds16(const f16* gptr, f16* ldsptr) {
    __builtin_amdgcn_global_load_lds(
        (const __attribute__((address_space(1))) u32*)gptr,
        (__attribute__((address_space(3))) u32*)ldsptr, 16, 0, 0);
}

// XOR-swizzled fragment read from unpadded [rows][32] f16 sub-tile
// (proven conflict-free: SQ_LDS_BANK_CONFLICT == 0).
#define FR(sbuf, row, q) \
    (*(const f16x8*)&sbuf[(row)*32 + (((q) ^ (((row) >> 1) & 3)) << 3)])

// ---------------- prep: router logits + x->f16 + weight transpose ----------
// Transpose part: 64x64 fp32 tiles, float4 loads, XOR-swizzled LDS,
// f16x8 (16B) coalesced stores.
#define KC 512
__global__ __launch_bounds__(256) void prep_kernel(
    const float* __restrict__ x, const float* __restrict__ wr,
    const float* __restrict__ w1, const float* __restrict__ w3,
    const float* __restrict__ w2, float* __restrict__ plogits,
    f16* __restrict__ x16,
    f16* __restrict__ w1t, f16* __restrict__ w3t, f16* __restrict__ w2t,
    int* __restrict__ zint)
{
    __shared__ float smem[NE*KC];   // 16 KiB; transpose uses all 64*64 floats
    int tid = threadIdx.x;
    int bi = blockIdx.x;
    if (bi == 0 && tid < 16) zint[tid] = 0;   // ghist[8] | gcur[8]
    if (bi < 1024) {
        int bx = bi & 511, by = bi >> 9;
        int kc0 = by * KC;
        for (int i = tid; i < NE*KC; i += 256) {
            int k = i >> 3, e = i & 7;
            smem[e*KC + k] = wr[(size_t)kc0*NE + i];
        }
        __syncthreads();
        int tok = bx*16 + (tid >> 4);
        int kl  = tid & 15;
        float acc[NE];
        #pragma unroll
        for (int e = 0; e < NE; e++) acc[e] = 0.f;
        const float* xrow = x + (size_t)tok*DIM + kc0;
        f16* xhrow = x16 + (size_t)tok*DIM + kc0;
        #pragma unroll
        for (int i = 0; i < KC/64; i++) {
            int kb = i*64 + kl*4;
            float4 xv = *(const float4*)(xrow + kb);
            f16x4 xh = { (f16)xv.x, (f16)xv.y, (f16)xv.z, (f16)xv.w };
            *(f16x4*)(xhrow + kb) = xh;
            #pragma unroll
            for (int e = 0; e < NE; e++) {
                float4 wv = *(const float4*)&smem[e*KC + kb];
                acc[e] += xv.x*wv.x + xv.y*wv.y + xv.z*wv.z + xv.w*wv.w;
            }
        }
        #pragma unroll
        for (int e = 0; e < NE; e++) {
            float v = acc[e];
            v += __shfl_xor(v, 1); v += __shfl_xor(v, 2);
            v += __shfl_xor(v, 4); v += __shfl_xor(v, 8);
            acc[e] = v;
        }
        if (kl == 0) {
            float* pp = plogits + ((size_t)by*NT + tok)*NE;
            float4 o0 = {acc[0], acc[1], acc[2], acc[3]};
            float4 o1 = {acc[4], acc[5], acc[6], acc[7]};
            *(float4*)pp = o0;
            *(float4*)(pp + 4) = o1;
        }
    } else {
        int tz = bi - 1024;
        int zx = tz & 127, zy = tz >> 7;      // 128 64x64 tiles per (tensor,e)
        int tensor = zy >> 3, e = zy & 7;
        const float* src; f16* dst; int R, C;
        if (tensor == 0)      { src = w1; dst = w1t; R = DIM; C = NH; }
        else if (tensor == 1) { src = w3; dst = w3t; R = DIM; C = NH; }
        else                  { src = w2; dst = w2t; R = NH; C = DIM; }
        src += (size_t)e * DIM * NH;
        dst += (size_t)e * DIM * NH;
        int tcols = C >> 6;
        int bx = zx % tcols, by = zx / tcols;
        int r0 = by*64, c0 = bx*64;
        #pragma unroll
        for (int p = 0; p < 4; p++) {
            int r = p*16 + (tid >> 4);
            int c = (tid & 15) << 2;
            float4 v = *(const float4*)&src[(size_t)(r0 + r)*C + c0 + c];
            *(float4*)&smem[r*64 + (c ^ (((r >> 3) & 7) << 2))] = v;
        }
        __syncthreads();
        #pragma unroll
        for (int pass = 0; pass < 2; pass++) {
            int s = pass*256 + tid;
            int h = s >> 3, a = s & 7, d0 = a << 3;
            int hs = h ^ (a << 2);
            f16x8 o;
            #pragma unroll
            for (int j = 0; j < 8; j++)
                o[j] = (f16)smem[(d0 + j)*64 + hs];
            *(f16x8*)&dst[(size_t)(c0 + h)*R + r0 + d0] = o;
        }
    }
}

// ---------------- route: softmax+top2 per token + global histogram ----------
__global__ __launch_bounds__(256) void route_kernel(
    const float* __restrict__ plogits, unsigned char* __restrict__ ge,
    float* __restrict__ gw, int* __restrict__ zint)
{
    __shared__ int lhist[NE];
    int tid = threadIdx.x;
    if (tid < NE) lhist[tid] = 0;
    __syncthreads();

    int t = blockIdx.x*256 + tid;
    const float* p0 = plogits + (size_t)t*NE;
    const float* p1 = plogits + (size_t)NT*NE + (size_t)t*NE;
    float4 a0 = *(const float4*)p0, a1 = *(const float4*)(p0+4);
    float4 b0 = *(const float4*)p1, b1 = *(const float4*)(p1+4);
    float l[NE] = { a0.x+b0.x, a0.y+b0.y, a0.z+b0.z, a0.w+b0.w,
                    a1.x+b1.x, a1.y+b1.y, a1.z+b1.z, a1.w+b1.w };
    float m = l[0];
    #pragma unroll
    for (int e = 1; e < NE; e++) m = fmaxf(m, l[e]);
    float s = 0.f;
    #pragma unroll
    for (int e = 0; e < NE; e++) { l[e] = __expf(l[e] - m); s += l[e]; }
    float inv = 1.f / s;
    int i0 = 0; float v0 = l[0];
    #pragma unroll
    for (int e = 1; e < NE; e++) if (l[e] > v0) { v0 = l[e]; i0 = e; }
    int i1 = -1; float v1 = -1.f;
    #pragma unroll
    for (int e = 0; e < NE; e++) if (e != i0 && l[e] > v1) { v1 = l[e]; i1 = e; }
    ge[2*t+0] = (unsigned char)i0; gw[2*t+0] = v0*inv;
    ge[2*t+1] = (unsigned char)i1; gw[2*t+1] = v1*inv;
    #pragma unroll
    for (int ee = 0; ee < NE; ee++) {
        int c = __popcll(__ballot(i0 == ee)) + __popcll(__ballot(i1 == ee));
        if ((tid & 63) == 0 && c) atomicAdd(&lhist[ee], c);
    }
    __syncthreads();
    if (tid < NE && lhist[tid]) atomicAdd(&zint[tid], lhist[tid]);   // ghist
}

// ---------------- scatter: ranked compaction via device-scope atomics -------
__global__ __launch_bounds__(256) void scatter_kernel(
    const unsigned char* __restrict__ ge, const float* __restrict__ gw,
    int* __restrict__ zint, int* __restrict__ offs, int* __restrict__ tok_ids,
    int* __restrict__ aid, float* __restrict__ row_gate)
{
    const int* ghist = zint;
    int* gcur = zint + 8;
    int tid = threadIdx.x;
    int loffs[NE]; int s = 0;
    #pragma unroll
    for (int e = 0; e < NE; e++) { loffs[e] = s; s += ghist[e]; }
    if (blockIdx.x == 0 && tid == 0) {
        #pragma unroll
        for (int e = 0; e < NE; e++) offs[e] = loffs[e];
        offs[NE] = s;
    }
    int id = blockIdx.x*256 + tid;
    int e = ge[id];
    float wv = gw[id];
    unsigned long long lt = (1ULL << (tid & 63)) - 1;
    int pos = 0;
    #pragma unroll
    for (int ee = 0; ee < NE; ee++) {
        unsigned long long mk = __ballot(e == ee);
        int cnt = __popcll(mk);
        int b = 0;
        if ((tid & 63) == 0 && cnt) b = atomicAdd(&gcur[ee], cnt);
        b = __shfl(b, 0);
        if (e == ee) pos = loffs[ee] + b + __popcll(mk & lt);
    }
    tok_ids[pos] = id >> 1;
    aid[pos] = id;
    row_gate[pos] = wv;
}

// ---------------- grouped GEMM tiles ----------------
// BK=64 as two 32-wide sub-tiles, full-drain schedule (proven fastest: R0/R4).
// Block mapping: e = bi>>10 (contiguous per-expert chunks) so consecutive
// blocks share the same B panel -> L2 hits on weight reads.

// GEMM1: BM=64 x BN=128 dual-B (w1 || w3), all-DMA staging (A from x16).
#define BM1 64
#define BN1 128
__global__ __launch_bounds__(256,3) void gemm1_kernel(
    const f16* __restrict__ x16, const int* __restrict__ tok_ids,
    const f16* __restrict__ w1t, const f16* __restrict__ w3t,
    f16* __restrict__ gbuf, const int* __restrict__ offs)
{
    int bi = blockIdx.x;
    int e  = bi >> 10;        // 1024 r_ slots per expert
    int r_ = bi & 1023;
    int nt = r_ & 3;          // NH/BN1 = 4
    int mt = r_ >> 2;         // 0..255 (covers worst-case 16384 rows)
    int off = offs[e];
    int n_e = offs[e+1] - off;
    if (mt*BM1 >= n_e) return;

    __shared__ f16 sA [2][BM1*32];   // 8 KB
    __shared__ f16 sB1[2][BN1*32];   // 16 KB
    __shared__ f16 sB3[2][BN1*32];   // 16 KB
    __shared__ int stok[BM1];

    int tid = threadIdx.x;
    if (tid < BM1) {
        int rloc = mt*BM1 + tid; rloc = rloc < n_e ? rloc : n_e - 1;
        stok[tid] = tok_ids[off + rloc];
    }
    __syncthreads();

    int lane = tid & 63, w = tid >> 6;
    int wcol = w*32;
    int q = lane >> 4, lm = lane & 15;

    // A staging (DMA): wave w covers rows [16w, 16w+16); both 32-col halves.
    int arow = w*16 + (lane >> 2);
    int ag   = (lane & 3) ^ ((arow >> 1) & 3);
    const f16* pa = x16 + (size_t)stok[arow]*DIM + ag*8;
    const int la = w*512 + lane*8;

    // B staging (DMA): wave w covers rows [32w, 32w+32) in 2 chunks of 16.
    int br0 = w*32 + (lane >> 2);
    int br1 = br0 + 16;
    int g0 = (lane & 3) ^ ((br0 >> 1) & 3);
    int g1 = (lane & 3) ^ ((br1 >> 1) & 3);
    const f16* w1p = w1t + ((size_t)e*NH + nt*BN1)*DIM;
    const f16* w3p = w3t + ((size_t)e*NH + nt*BN1)*DIM;
    const f16* pb1_0 = w1p + (size_t)br0*DIM + g0*8;
    const f16* pb1_1 = w1p + (size_t)br1*DIM + g1*8;
    const f16* pb3_0 = w3p + (size_t)br0*DIM + g0*8;
    const f16* pb3_1 = w3p + (size_t)br1*DIM + g1*8;
    const int lofs0 = br0*32 + ((lane & 3) << 3);
    const int lofs1 = br1*32 + ((lane & 3) << 3);

    f32x4 acc1[4][2], acc3[4][2];
    #pragma unroll
    for (int a = 0; a < 4; a++)
        #pragma unroll
        for (int b = 0; b < 2; b++) {
            acc1[a][b] = (f32x4){0.f,0.f,0.f,0.f};
            acc3[a][b] = (f32x4){0.f,0.f,0.f,0.f};
        }

    for (int k0 = 0; k0 < DIM; k0 += 64) {
        __syncthreads();          // prev-tile FR reads complete
        gl2lds16(pa + k0,         &sA [0][la]);
        gl2lds16(pa + k0 + 32,    &sA [1][la]);
        gl2lds16(pb1_0 + k0,      &sB1[0][lofs0]);
        gl2lds16(pb1_1 + k0,      &sB1[0][lofs1]);
        gl2lds16(pb1_0 + k0 + 32, &sB1[1][lofs0]);
        gl2lds16(pb1_1 + k0 + 32, &sB1[1][lofs1]);
        gl2lds16(pb3_0 + k0,      &sB3[0][lofs0]);
        gl2lds16(pb3_1 + k0,      &sB3[0][lofs1]);
        gl2lds16(pb3_0 + k0 + 32, &sB3[1][lofs0]);
        gl2lds16(pb3_1 + k0 + 32, &sB3[1][lofs1]);
        __syncthreads();          // drains DMA
        #pragma unroll
        for (int ks = 0; ks < 2; ks++) {
            f16x8 aF[4], b1F[2], b3F[2];
            #pragma unroll
            for (int s = 0; s < 4; s++) aF[s] = FR(sA[ks], s*16 + lm, q);
            #pragma unroll
            for (int c = 0; c < 2; c++) {
                b1F[c] = FR(sB1[ks], wcol + c*16 + lm, q);
                b3F[c] = FR(sB3[ks], wcol + c*16 + lm, q);
            }
            #pragma unroll
            for (int sr = 0; sr < 4; sr++)
                #pragma unroll
                for (int sc = 0; sc < 2; sc++) {
                    acc1[sr][sc] = __builtin_amdgcn_mfma_f32_16x16x32_f16(aF[sr], b1F[sc], acc1[sr][sc], 0, 0, 0);
                    acc3[sr][sc] = __builtin_amdgcn_mfma_f32_16x16x32_f16(aF[sr], b3F[sc], acc3[sr][sc], 0, 0, 0);
                }
        }
    }
    // epilogue: silu(h1)*h3 -> f16 gbuf.  C/D: col=lane&15, row=(lane>>4)*4+reg
    #pragma unroll
    for (int sr = 0; sr < 4; sr++) {
        #pragma unroll
        for (int reg = 0; reg < 4; reg++) {
            int row = mt*BM1 + sr*16 + q*4 + reg;
            if (row < n_e) {
                #pragma unroll
                for (int sc = 0; sc < 2; sc++) {
                    int col = nt*BN1 + wcol + sc*16 + lm;
                    float h1 = acc1[sr][sc][reg];
                    float h3 = acc3[sr][sc][reg];
                    float gv = h1 / (1.f + __expf(-h1)) * h3;
                    gbuf[(size_t)(off + row)*NH + col] = (f16)gv;
                }
            }
        }
    }
}

// GEMM2: ybuf[aid[row]] = gate * (G @ W2). Full DMA staging, BK=64, 8 iters.
// launch_bounds (256,4): LDS 33.8 KB allows 4 blocks/CU (was capped at 3).
#define BM 128
#define BN 128
__global__ __launch_bounds__(256,4) void gemm2_kernel(
    const f16* __restrict__ gbuf, const f16* __restrict__ w2t,
    const int* __restrict__ offs, const int* __restrict__ aid,
    const float* __restrict__ row_gate, f16* __restrict__ ybuf)
{
    int bi = blockIdx.x;
    int e  = bi >> 10;        // contiguous per-expert chunks
    int r_ = bi & 1023;
    int nt = r_ & 7;          // DIM/BN = 8
    int mt = r_ >> 3;         // 0..127 (covers worst-case 16384 rows)
    int off = offs[e];
    int n_e = offs[e+1] - off;
    if (mt*BM >= n_e) return;

    __shared__ f16 sA[2][BM*32];   // 16 KB
    __shared__ f16 sB[2][BN*32];   // 16 KB
    __shared__ int said[BM];
    __shared__ float sgate[BM];

    int tid = threadIdx.x;
    if (tid < BM) {
        int rloc = mt*BM + tid;
        if (rloc < n_e) { said[tid] = aid[off + rloc]; sgate[tid] = row_gate[off + rloc]; }
        else            { said[tid] = 0; sgate[tid] = 0.f; }
    }

    int lane = tid & 63, w = tid >> 6;
    int wrow = (w >> 1)*64, wcol = (w & 1)*64;
    int q = lane >> 4, lm = lane & 15;

    int lr0 = w*32 + (lane >> 2);
    int lr1 = lr0 + 16;
    int g0 = (lane & 3) ^ ((lr0 >> 1) & 3);
    int g1 = (lane & 3) ^ ((lr1 >> 1) & 3);
    int ga0 = mt*BM + lr0; ga0 = ga0 < n_e ? ga0 : n_e - 1;
    int ga1 = mt*BM + lr1; ga1 = ga1 < n_e ? ga1 : n_e - 1;
    const f16* pA0 = gbuf + (size_t)(off + ga0)*NH + g0*8;
    const f16* pA1 = gbuf + (size_t)(off + ga1)*NH + g1*8;
    const f16* w2p = w2t + ((size_t)e*DIM + nt*BN)*NH;
    const f16* pB0 = w2p + (size_t)lr0*NH + g0*8;
    const f16* pB1 = w2p + (size_t)lr1*NH + g1*8;
    const int lofs0 = lr0*32 + ((lane & 3) << 3);
    const int lofs1 = lr1*32 + ((lane & 3) << 3);

    f32x4 acc[4][4];
    #pragma unroll
    for (int a = 0; a < 4; a++)
        #pragma unroll
        for (int b = 0; b < 4; b++) acc[a][b] = (f32x4){0.f,0.f,0.f,0.f};

    __syncthreads();   // covers said/sgate writes

    for (int k0 = 0; k0 < NH; k0 += 64) {
        gl2lds16(pA0 + k0,      &sA[0][lofs0]);
        gl2lds16(pA1 + k0,      &sA[0][lofs1]);
        gl2lds16(pA0 + k0 + 32, &sA[1][lofs0]);
        gl2lds16(pA1 + k0 + 32, &sA[1][lofs1]);
        gl2lds16(pB0 + k0,      &sB[0][lofs0]);
        gl2lds16(pB1 + k0,      &sB[0][lofs1]);
        gl2lds16(pB0 + k0 + 32, &sB[1][lofs0]);
        gl2lds16(pB1 + k0 + 32, &sB[1][lofs1]);
        __syncthreads();   // drains vmcnt
        #pragma unroll
        for (int ks = 0; ks < 2; ks++) {
            f16x8 aF[4], bF[4];
            #pragma unroll
            for (int s = 0; s < 4; s++) {
                aF[s] = FR(sA[ks], wrow + s*16 + lm, q);
                bF[s] = FR(sB[ks], wcol + s*16 + lm, q);
            }
            #pragma unroll
            for (int sr = 0; sr < 4; sr++)
                #pragma unroll
                for (int sc = 0; sc < 4; sc++)
                    acc[sr][sc] = __builtin_amdgcn_mfma_f32_16x16x32_f16(aF[sr], bF[sc], acc[sr][sc], 0, 0, 0);
        }
        __syncthreads();   // reads done before next iter's DMA
    }
    #pragma unroll
    for (int sr = 0; sr < 4; sr++) {
        #pragma unroll
        for (int reg = 0; reg < 4; reg++) {
            int lrow = wrow + sr*16 + q*4 + reg;
            if (mt*BM + lrow < n_e) {
                int id = said[lrow];
                float wgt = sgate[lrow];
                #pragma unroll
                for (int sc = 0; sc < 4; sc++) {
                    int col = nt*BN + wcol + sc*16 + lm;
                    ybuf[(size_t)id*DIM + col] = (f16)(wgt * acc[sr][sc][reg]);
                }
            }
        }
    }
}

// ---------------- combine: out[t] = ybuf[2t] + ybuf[2t+1] ----------------
__global__ __launch_bounds__(256) void combine_kernel(
    const f16* __restrict__ ybuf, float* __restrict__ out)
{
    int gid = blockIdx.x*256 + threadIdx.x;
    int t = gid >> 7;
    int c = (gid & 127) << 3;
    f16x8 y0 = *(const f16x8*)(ybuf + ((size_t)2*t)*DIM + c);
    f16x8 y1 = *(const f16x8*)(ybuf + ((size_t)2*t+1)*DIM + c);
    float* op = out + (size_t)t*DIM + c;
    float4 o0 = { (float)y0[0] + (float)y1[0], (float)y0[1] + (float)y1[1],
                  (float)y0[2] + (float)y1[2], (float)y0[3] + (float)y1[3] };
    float4 o1 = { (float)y0[4] + (float)y1[4], (float)y0[5] + (float)y1[5],
                  (float)y0[6] + (float)y1[6], (float)y0[7] + (float)y1[7] };
    *(float4*)op = o0;
    *(float4*)(op + 4) = o1;
}

extern "C" void kernel_launch(void* const* d_in, const int* in_sizes, int n_in,
                              void* d_out, int out_size, void* d_ws, size_t ws_size,
                              hipStream_t stream)
{
    const float* x  = (const float*)d_in[0];
    const float* wr = (const float*)d_in[1];
    const float* w1 = (const float*)d_in[2];
    const float* w2 = (const float*)d_in[3];
    const float* w3 = (const float*)d_in[4];
    float* out = (float*)d_out;

    char* ws = (char*)d_ws;
    f16* ybuf    = (f16*)ws;        ws += (size_t)NROWS*DIM*sizeof(f16);   // 32 MiB (writer: gemm2)
    f16* w1t     = (f16*)ws;        ws += (size_t)NE*NH*DIM*sizeof(f16);   // 8 MiB (writer: prep)
    f16* w3t     = (f16*)ws;        ws += (size_t)NE*NH*DIM*sizeof(f16);   // 8 MiB (writer: prep)
    f16* w2t     = (f16*)ws;        ws += (size_t)NE*DIM*NH*sizeof(f16);   // 8 MiB (writer: prep)
    f16* gbuf    = (f16*)ws;        ws += (size_t)NROWS*NH*sizeof(f16);    // 16 MiB (writer: gemm1)
    float* plogits = (float*)ws;    ws += (size_t)2*NT*NE*4;               // 512 KiB (writer: prep)
    int* tok_ids = (int*)ws;        ws += (size_t)NROWS*4;                 // (writer: scatter)
    int* aid     = (int*)ws;        ws += (size_t)NROWS*4;
    float* row_gate = (float*)ws;   ws += (size_t)NROWS*4;
    int* offs    = (int*)ws;        ws += 64;
    unsigned char* ge = (unsigned char*)ws; ws += (size_t)NROWS;           // (writer: route)
    float* gw    = (float*)ws;      ws += (size_t)NROWS*4;
    int* zint    = (int*)ws;        ws += 64;                              // ghist[8]|gcur[8]
    if (ws_size < (size_t)(ws - (char*)d_ws)) return;  // ~72.8 MB needed

    // x16 aliases ybuf: prep writes it, gemm1 reads it, then gemm2 overwrites
    // the region with ybuf (x16 dead by then). 16 MiB, zero workspace growth.
    f16* x16 = ybuf;

    prep_kernel<<<1024 + 3072, 256, 0, stream>>>(x, wr, w1, w3, w2,
                                                 plogits, x16, w1t, w3t, w2t, zint);
    route_kernel<<<NT/256, 256, 0, stream>>>(plogits, ge, gw, zint);
    scatter_kernel<<<NROWS/256, 256, 0, stream>>>(ge, gw, zint, offs,
                                                  tok_ids, aid, row_gate);
    gemm1_kernel<<<8192, 256, 0, stream>>>(x16, tok_ids, w1t, w3t, gbuf, offs);
    gemm2_kernel<<<8192, 256, 0, stream>>>(gbuf, w2t, offs, aid, row_gate, ybuf);
    combine_kernel<<<(NT*(DIM/8))/256, 256, 0, stream>>>(ybuf, out);
}

// Round 7
// 238.588 us; speedup vs baseline: 1.2126x; 1.0844x over previous
//
#include <hip/hip_runtime.h>

#define NT    8192      // tokens (B*S)
#define DIM   1024      // d_model
#define NE    8         // experts
#define NH    512       // hidden
#define NROWS (NT*2)    // token-expert assignments (top_k=2)

typedef _Float16 f16;
typedef unsigned int u32;
typedef __attribute__((ext_vector_type(8))) _Float16 f16x8;
typedef __attribute__((ext_vector_type(4))) _Float16 f16x4;
typedef __attribute__((ext_vector_type(2))) _Float16 f16x2;
typedef __attribute__((ext_vector_type(4))) float f32x4;

// global -> LDS direct DMA, 16B per lane (wave-uniform base + lane*16).
__device__ __forceinline__ void gl2lds16(const f16* gptr, f16* ldsptr) {
    __builtin_amdgcn_global_load_lds(
        (const __attribute__((address_space(1))) u32*)gptr,
        (__attribute__((address_space(3))) u32*)ldsptr, 16, 0, 0);
}

// XOR-swizzled fragment read from unpadded [rows][32] f16 sub-tile
// (proven conflict-free: SQ_LDS_BANK_CONFLICT == 0).
#define FR(sbuf, row, q) \
    (*(const f16x8*)&sbuf[(row)*32 + (((q) ^ (((row) >> 1) & 3)) << 3)])

// ---------------- prep: router logits + x->f16 + weight transpose ----------
#define KC 512
__global__ __launch_bounds__(256) void prep_kernel(
    const float* __restrict__ x, const float* __restrict__ wr,
    const float* __restrict__ w1, const float* __restrict__ w3,
    const float* __restrict__ w2, float* __restrict__ plogits,
    f16* __restrict__ x16,
    f16* __restrict__ w1t, f16* __restrict__ w3t, f16* __restrict__ w2t,
    int* __restrict__ zint)
{
    __shared__ float smem[NE*KC];   // 16 KiB; transpose uses all 64*64 floats
    int tid = threadIdx.x;
    int bi = blockIdx.x;
    if (bi == 0 && tid < 16) zint[tid] = 0;   // ghist[8] | gcur[8]
    if (bi < 1024) {
        int bx = bi & 511, by = bi >> 9;
        int kc0 = by * KC;
        for (int i = tid; i < NE*KC; i += 256) {
            int k = i >> 3, e = i & 7;
            smem[e*KC + k] = wr[(size_t)kc0*NE + i];
        }
        __syncthreads();
        int tok = bx*16 + (tid >> 4);
        int kl  = tid & 15;
        float acc[NE];
        #pragma unroll
        for (int e = 0; e < NE; e++) acc[e] = 0.f;
        const float* xrow = x + (size_t)tok*DIM + kc0;
        f16* xhrow = x16 + (size_t)tok*DIM + kc0;
        #pragma unroll
        for (int i = 0; i < KC/64; i++) {
            int kb = i*64 + kl*4;
            float4 xv = *(const float4*)(xrow + kb);
            f16x4 xh = { (f16)xv.x, (f16)xv.y, (f16)xv.z, (f16)xv.w };
            *(f16x4*)(xhrow + kb) = xh;
            #pragma unroll
            for (int e = 0; e < NE; e++) {
                float4 wv = *(const float4*)&smem[e*KC + kb];
                acc[e] += xv.x*wv.x + xv.y*wv.y + xv.z*wv.z + xv.w*wv.w;
            }
        }
        #pragma unroll
        for (int e = 0; e < NE; e++) {
            float v = acc[e];
            v += __shfl_xor(v, 1); v += __shfl_xor(v, 2);
            v += __shfl_xor(v, 4); v += __shfl_xor(v, 8);
            acc[e] = v;
        }
        if (kl == 0) {
            float* pp = plogits + ((size_t)by*NT + tok)*NE;
            float4 o0 = {acc[0], acc[1], acc[2], acc[3]};
            float4 o1 = {acc[4], acc[5], acc[6], acc[7]};
            *(float4*)pp = o0;
            *(float4*)(pp + 4) = o1;
        }
    } else {
        int tz = bi - 1024;
        int zx = tz & 127, zy = tz >> 7;      // 128 64x64 tiles per (tensor,e)
        int tensor = zy >> 3, e = zy & 7;
        const float* src; f16* dst; int R, C;
        if (tensor == 0)      { src = w1; dst = w1t; R = DIM; C = NH; }
        else if (tensor == 1) { src = w3; dst = w3t; R = DIM; C = NH; }
        else                  { src = w2; dst = w2t; R = NH; C = DIM; }
        src += (size_t)e * DIM * NH;
        dst += (size_t)e * DIM * NH;
        int tcols = C >> 6;
        int bx = zx % tcols, by = zx / tcols;
        int r0 = by*64, c0 = bx*64;
        #pragma unroll
        for (int p = 0; p < 4; p++) {
            int r = p*16 + (tid >> 4);
            int c = (tid & 15) << 2;
            float4 v = *(const float4*)&src[(size_t)(r0 + r)*C + c0 + c];
            *(float4*)&smem[r*64 + (c ^ (((r >> 3) & 7) << 2))] = v;
        }
        __syncthreads();
        #pragma unroll
        for (int pass = 0; pass < 2; pass++) {
            int s = pass*256 + tid;
            int h = s >> 3, a = s & 7, d0 = a << 3;
            int hs = h ^ (a << 2);
            f16x8 o;
            #pragma unroll
            for (int j = 0; j < 8; j++)
                o[j] = (f16)smem[(d0 + j)*64 + hs];
            *(f16x8*)&dst[(size_t)(c0 + h)*R + r0 + d0] = o;
        }
    }
}

// ---------------- route: softmax+top2 per token + global histogram ----------
__global__ __launch_bounds__(256) void route_kernel(
    const float* __restrict__ plogits, unsigned char* __restrict__ ge,
    float* __restrict__ gw, int* __restrict__ zint)
{
    __shared__ int lhist[NE];
    int tid = threadIdx.x;
    if (tid < NE) lhist[tid] = 0;
    __syncthreads();

    int t = blockIdx.x*256 + tid;
    const float* p0 = plogits + (size_t)t*NE;
    const float* p1 = plogits + (size_t)NT*NE + (size_t)t*NE;
    float4 a0 = *(const float4*)p0, a1 = *(const float4*)(p0+4);
    float4 b0 = *(const float4*)p1, b1 = *(const float4*)(p1+4);
    float l[NE] = { a0.x+b0.x, a0.y+b0.y, a0.z+b0.z, a0.w+b0.w,
                    a1.x+b1.x, a1.y+b1.y, a1.z+b1.z, a1.w+b1.w };
    float m = l[0];
    #pragma unroll
    for (int e = 1; e < NE; e++) m = fmaxf(m, l[e]);
    float s = 0.f;
    #pragma unroll
    for (int e = 0; e < NE; e++) { l[e] = __expf(l[e] - m); s += l[e]; }
    float inv = 1.f / s;
    int i0 = 0; float v0 = l[0];
    #pragma unroll
    for (int e = 1; e < NE; e++) if (l[e] > v0) { v0 = l[e]; i0 = e; }
    int i1 = -1; float v1 = -1.f;
    #pragma unroll
    for (int e = 0; e < NE; e++) if (e != i0 && l[e] > v1) { v1 = l[e]; i1 = e; }
    ge[2*t+0] = (unsigned char)i0; gw[2*t+0] = v0*inv;
    ge[2*t+1] = (unsigned char)i1; gw[2*t+1] = v1*inv;
    #pragma unroll
    for (int ee = 0; ee < NE; ee++) {
        int c = __popcll(__ballot(i0 == ee)) + __popcll(__ballot(i1 == ee));
        if ((tid & 63) == 0 && c) atomicAdd(&lhist[ee], c);
    }
    __syncthreads();
    if (tid < NE && lhist[tid]) atomicAdd(&zint[tid], lhist[tid]);   // ghist
}

// ---------------- scatter: ranked compaction via device-scope atomics -------
__global__ __launch_bounds__(256) void scatter_kernel(
    const unsigned char* __restrict__ ge, const float* __restrict__ gw,
    int* __restrict__ zint, int* __restrict__ offs, int* __restrict__ tok_ids,
    int* __restrict__ aid, float* __restrict__ row_gate)
{
    const int* ghist = zint;
    int* gcur = zint + 8;
    int tid = threadIdx.x;
    int loffs[NE]; int s = 0;
    #pragma unroll
    for (int e = 0; e < NE; e++) { loffs[e] = s; s += ghist[e]; }
    if (blockIdx.x == 0 && tid == 0) {
        #pragma unroll
        for (int e = 0; e < NE; e++) offs[e] = loffs[e];
        offs[NE] = s;
    }
    int id = blockIdx.x*256 + tid;
    int e = ge[id];
    float wv = gw[id];
    unsigned long long lt = (1ULL << (tid & 63)) - 1;
    int pos = 0;
    #pragma unroll
    for (int ee = 0; ee < NE; ee++) {
        unsigned long long mk = __ballot(e == ee);
        int cnt = __popcll(mk);
        int b = 0;
        if ((tid & 63) == 0 && cnt) b = atomicAdd(&gcur[ee], cnt);
        b = __shfl(b, 0);
        if (e == ee) pos = loffs[ee] + b + __popcll(mk & lt);
    }
    tok_ids[pos] = id >> 1;
    aid[pos] = id;
    row_gate[pos] = wv;
}

// ---------------- grouped GEMM tiles ----------------
// BK=64 as two 32-wide sub-tiles, full-drain schedule.
// e = bi&7: expert == bi mod 8 == XCD under round-robin dispatch -> each
// XCD's L2 holds exactly one expert's weight panels (R6 post-mortem).

// GEMM1: BM=128 x BN=64 dual-B (w1 || w3). 256 B staged per MFMA (m97 ratio),
// 8 DMAs/wave/K-step, LDS 32.5 KB -> 4 blocks/CU.
#define BM1 128
#define BN1 64
__global__ __launch_bounds__(256,3) void gemm1_kernel(
    const f16* __restrict__ x16, const int* __restrict__ tok_ids,
    const f16* __restrict__ w1t, const f16* __restrict__ w3t,
    f16* __restrict__ gbuf, const int* __restrict__ offs)
{
    int bi = blockIdx.x;
    int e  = bi & 7;
    int r_ = bi >> 3;
    int nt = r_ & 7;          // NH/BN1 = 8
    int mt = r_ >> 3;         // 0..63 covers worst-case 8192 rows/expert
    int off = offs[e];
    int n_e = offs[e+1] - off;
    if (mt*BM1 >= n_e) return;

    __shared__ f16 sA [2][BM1*32];   // 16 KB
    __shared__ f16 sB1[2][BN1*32];   // 8 KB
    __shared__ f16 sB3[2][BN1*32];   // 8 KB
    __shared__ int stok[BM1];

    int tid = threadIdx.x;
    if (tid < BM1) {
        int rloc = mt*BM1 + tid; rloc = rloc < n_e ? rloc : n_e - 1;
        stok[tid] = tok_ids[off + rloc];
    }
    __syncthreads();

    int lane = tid & 63, w = tid >> 6;
    int wrow = (w >> 1)*64, wcol = (w & 1)*32;
    int q = lane >> 4, lm = lane & 15;

    // A staging (DMA, gathered): wave w covers rows [32w, 32w+32) in 2
    // chunks of 16 (same pattern as gemm2's sA, proven conflict-free).
    int lr0 = w*32 + (lane >> 2);
    int lr1 = lr0 + 16;
    int gA0 = (lane & 3) ^ ((lr0 >> 1) & 3);
    int gA1 = (lane & 3) ^ ((lr1 >> 1) & 3);
    const f16* pA0 = x16 + (size_t)stok[lr0]*DIM + gA0*8;
    const f16* pA1 = x16 + (size_t)stok[lr1]*DIM + gA1*8;
    const int lofs0 = lr0*32 + ((lane & 3) << 3);
    const int lofs1 = lr1*32 + ((lane & 3) << 3);

    // B staging (DMA): wave w covers rows [16w, 16w+16) of each B.
    int br = w*16 + (lane >> 2);
    int gB = (lane & 3) ^ ((br >> 1) & 3);
    const f16* w1p = w1t + ((size_t)e*NH + nt*BN1)*DIM;
    const f16* w3p = w3t + ((size_t)e*NH + nt*BN1)*DIM;
    const f16* pb1 = w1p + (size_t)br*DIM + gB*8;
    const f16* pb3 = w3p + (size_t)br*DIM + gB*8;
    const int bofs = br*32 + ((lane & 3) << 3);

    f32x4 acc1[4][2], acc3[4][2];
    #pragma unroll
    for (int a = 0; a < 4; a++)
        #pragma unroll
        for (int b = 0; b < 2; b++) {
            acc1[a][b] = (f32x4){0.f,0.f,0.f,0.f};
            acc3[a][b] = (f32x4){0.f,0.f,0.f,0.f};
        }

    for (int k0 = 0; k0 < DIM; k0 += 64) {
        __syncthreads();          // prev-tile FR reads complete
        gl2lds16(pA0 + k0,      &sA [0][lofs0]);
        gl2lds16(pA1 + k0,      &sA [0][lofs1]);
        gl2lds16(pA0 + k0 + 32, &sA [1][lofs0]);
        gl2lds16(pA1 + k0 + 32, &sA [1][lofs1]);
        gl2lds16(pb1 + k0,      &sB1[0][bofs]);
        gl2lds16(pb1 + k0 + 32, &sB1[1][bofs]);
        gl2lds16(pb3 + k0,      &sB3[0][bofs]);
        gl2lds16(pb3 + k0 + 32, &sB3[1][bofs]);
        __syncthreads();          // drains DMA
        #pragma unroll
        for (int ks = 0; ks < 2; ks++) {
            f16x8 aF[4], b1F[2], b3F[2];
            #pragma unroll
            for (int s = 0; s < 4; s++) aF[s] = FR(sA[ks], wrow + s*16 + lm, q);
            #pragma unroll
            for (int c = 0; c < 2; c++) {
                b1F[c] = FR(sB1[ks], wcol + c*16 + lm, q);
                b3F[c] = FR(sB3[ks], wcol + c*16 + lm, q);
            }
            #pragma unroll
            for (int sr = 0; sr < 4; sr++)
                #pragma unroll
                for (int sc = 0; sc < 2; sc++) {
                    acc1[sr][sc] = __builtin_amdgcn_mfma_f32_16x16x32_f16(aF[sr], b1F[sc], acc1[sr][sc], 0, 0, 0);
                    acc3[sr][sc] = __builtin_amdgcn_mfma_f32_16x16x32_f16(aF[sr], b3F[sc], acc3[sr][sc], 0, 0, 0);
                }
        }
    }
    // epilogue: silu(h1)*h3 -> f16 gbuf.  C/D: col=lane&15, row=(lane>>4)*4+reg
    #pragma unroll
    for (int sr = 0; sr < 4; sr++) {
        #pragma unroll
        for (int reg = 0; reg < 4; reg++) {
            int row = mt*BM1 + wrow + sr*16 + q*4 + reg;
            if (row < n_e) {
                #pragma unroll
                for (int sc = 0; sc < 2; sc++) {
                    int col = nt*BN1 + wcol + sc*16 + lm;
                    float h1 = acc1[sr][sc][reg];
                    float h3 = acc3[sr][sc][reg];
                    float gv = h1 / (1.f + __expf(-h1)) * h3;
                    gbuf[(size_t)(off + row)*NH + col] = (f16)gv;
                }
            }
        }
    }
}

// GEMM2: ybuf[aid[row]] = gate * (G @ W2). Full DMA staging, BK=64, 8 iters.
#define BM 128
#define BN 128
__global__ __launch_bounds__(256,3) void gemm2_kernel(
    const f16* __restrict__ gbuf, const f16* __restrict__ w2t,
    const int* __restrict__ offs, const int* __restrict__ aid,
    const float* __restrict__ row_gate, f16* __restrict__ ybuf)
{
    int bi = blockIdx.x;
    int e  = bi & 7;
    int r_ = bi >> 3;
    int nt = r_ & 7;          // DIM/BN = 8
    int mt = r_ >> 3;
    int off = offs[e];
    int n_e = offs[e+1] - off;
    if (mt*BM >= n_e) return;

    __shared__ f16 sA[2][BM*32];   // 16 KB
    __shared__ f16 sB[2][BN*32];   // 16 KB
    __shared__ int said[BM];
    __shared__ float sgate[BM];

    int tid = threadIdx.x;
    if (tid < BM) {
        int rloc = mt*BM + tid;
        if (rloc < n_e) { said[tid] = aid[off + rloc]; sgate[tid] = row_gate[off + rloc]; }
        else            { said[tid] = 0; sgate[tid] = 0.f; }
    }

    int lane = tid & 63, w = tid >> 6;
    int wrow = (w >> 1)*64, wcol = (w & 1)*64;
    int q = lane >> 4, lm = lane & 15;

    int lr0 = w*32 + (lane >> 2);
    int lr1 = lr0 + 16;
    int g0 = (lane & 3) ^ ((lr0 >> 1) & 3);
    int g1 = (lane & 3) ^ ((lr1 >> 1) & 3);
    int ga0 = mt*BM + lr0; ga0 = ga0 < n_e ? ga0 : n_e - 1;
    int ga1 = mt*BM + lr1; ga1 = ga1 < n_e ? ga1 : n_e - 1;
    const f16* pA0 = gbuf + (size_t)(off + ga0)*NH + g0*8;
    const f16* pA1 = gbuf + (size_t)(off + ga1)*NH + g1*8;
    const f16* w2p = w2t + ((size_t)e*DIM + nt*BN)*NH;
    const f16* pB0 = w2p + (size_t)lr0*NH + g0*8;
    const f16* pB1 = w2p + (size_t)lr1*NH + g1*8;
    const int lofs0 = lr0*32 + ((lane & 3) << 3);
    const int lofs1 = lr1*32 + ((lane & 3) << 3);

    f32x4 acc[4][4];
    #pragma unroll
    for (int a = 0; a < 4; a++)
        #pragma unroll
        for (int b = 0; b < 4; b++) acc[a][b] = (f32x4){0.f,0.f,0.f,0.f};

    __syncthreads();   // covers said/sgate writes

    for (int k0 = 0; k0 < NH; k0 += 64) {
        gl2lds16(pA0 + k0,      &sA[0][lofs0]);
        gl2lds16(pA1 + k0,      &sA[0][lofs1]);
        gl2lds16(pA0 + k0 + 32, &sA[1][lofs0]);
        gl2lds16(pA1 + k0 + 32, &sA[1][lofs1]);
        gl2lds16(pB0 + k0,      &sB[0][lofs0]);
        gl2lds16(pB1 + k0,      &sB[0][lofs1]);
        gl2lds16(pB0 + k0 + 32, &sB[1][lofs0]);
        gl2lds16(pB1 + k0 + 32, &sB[1][lofs1]);
        __syncthreads();   // drains vmcnt
        #pragma unroll
        for (int ks = 0; ks < 2; ks++) {
            f16x8 aF[4], bF[4];
            #pragma unroll
            for (int s = 0; s < 4; s++) {
                aF[s] = FR(sA[ks], wrow + s*16 + lm, q);
                bF[s] = FR(sB[ks], wcol + s*16 + lm, q);
            }
            #pragma unroll
            for (int sr = 0; sr < 4; sr++)
                #pragma unroll
                for (int sc = 0; sc < 4; sc++)
                    acc[sr][sc] = __builtin_amdgcn_mfma_f32_16x16x32_f16(aF[sr], bF[sc], acc[sr][sc], 0, 0, 0);
        }
        __syncthreads();   // reads done before next iter's DMA
    }
    #pragma unroll
    for (int sr = 0; sr < 4; sr++) {
        #pragma unroll
        for (int reg = 0; reg < 4; reg++) {
            int lrow = wrow + sr*16 + q*4 + reg;
            if (mt*BM + lrow < n_e) {
                int id = said[lrow];
                float wgt = sgate[lrow];
                #pragma unroll
                for (int sc = 0; sc < 4; sc++) {
                    int col = nt*BN + wcol + sc*16 + lm;
                    ybuf[(size_t)id*DIM + col] = (f16)(wgt * acc[sr][sc][reg]);
                }
            }
        }
    }
}

// ---------------- combine: out[t] = ybuf[2t] + ybuf[2t+1] ----------------
__global__ __launch_bounds__(256) void combine_kernel(
    const f16* __restrict__ ybuf, float* __restrict__ out)
{
    int gid = blockIdx.x*256 + threadIdx.x;
    int t = gid >> 7;
    int c = (gid & 127) << 3;
    f16x8 y0 = *(const f16x8*)(ybuf + ((size_t)2*t)*DIM + c);
    f16x8 y1 = *(const f16x8*)(ybuf + ((size_t)2*t+1)*DIM + c);
    float* op = out + (size_t)t*DIM + c;
    float4 o0 = { (float)y0[0] + (float)y1[0], (float)y0[1] + (float)y1[1],
                  (float)y0[2] + (float)y1[2], (float)y0[3] + (float)y1[3] };
    float4 o1 = { (float)y0[4] + (float)y1[4], (float)y0[5] + (float)y1[5],
                  (float)y0[6] + (float)y1[6], (float)y0[7] + (float)y1[7] };
    *(float4*)op = o0;
    *(float4*)(op + 4) = o1;
}

extern "C" void kernel_launch(void* const* d_in, const int* in_sizes, int n_in,
                              void* d_out, int out_size, void* d_ws, size_t ws_size,
                              hipStream_t stream)
{
    const float* x  = (const float*)d_in[0];
    const float* wr = (const float*)d_in[1];
    const float* w1 = (const float*)d_in[2];
    const float* w2 = (const float*)d_in[3];
    const float* w3 = (const float*)d_in[4];
    float* out = (float*)d_out;

    char* ws = (char*)d_ws;
    f16* ybuf    = (f16*)ws;        ws += (size_t)NROWS*DIM*sizeof(f16);   // 32 MiB (writer: gemm2)
    f16* w1t     = (f16*)ws;        ws += (size_t)NE*NH*DIM*sizeof(f16);   // 8 MiB (writer: prep)
    f16* w3t     = (f16*)ws;        ws += (size_t)NE*NH*DIM*sizeof(f16);   // 8 MiB (writer: prep)
    f16* w2t     = (f16*)ws;        ws += (size_t)NE*DIM*NH*sizeof(f16);   // 8 MiB (writer: prep)
    f16* gbuf    = (f16*)ws;        ws += (size_t)NROWS*NH*sizeof(f16);    // 16 MiB (writer: gemm1)
    float* plogits = (float*)ws;    ws += (size_t)2*NT*NE*4;               // 512 KiB (writer: prep)
    int* tok_ids = (int*)ws;        ws += (size_t)NROWS*4;                 // (writer: scatter)
    int* aid     = (int*)ws;        ws += (size_t)NROWS*4;
    float* row_gate = (float*)ws;   ws += (size_t)NROWS*4;
    int* offs    = (int*)ws;        ws += 64;
    unsigned char* ge = (unsigned char*)ws; ws += (size_t)NROWS;           // (writer: route)
    float* gw    = (float*)ws;      ws += (size_t)NROWS*4;
    int* zint    = (int*)ws;        ws += 64;                              // ghist[8]|gcur[8]
    if (ws_size < (size_t)(ws - (char*)d_ws)) return;  // ~72.8 MB needed

    // x16 aliases ybuf: prep writes it, gemm1 reads it, then gemm2 overwrites
    // the region with ybuf (x16 dead by then). 16 MiB, zero workspace growth.
    f16* x16 = ybuf;

    prep_kernel<<<1024 + 3072, 256, 0, stream>>>(x, wr, w1, w3, w2,
                                                 plogits, x16, w1t, w3t, w2t, zint);
    route_kernel<<<NT/256, 256, 0, stream>>>(plogits, ge, gw, zint);
    scatter_kernel<<<NROWS/256, 256, 0, stream>>>(ge, gw, zint, offs,
                                                  tok_ids, aid, row_gate);
    gemm1_kernel<<<4096, 256, 0, stream>>>(x16, tok_ids, w1t, w3t, gbuf, offs);
    gemm2_kernel<<<8192, 256, 0, stream>>>(gbuf, w2t, offs, aid, row_gate, ybuf);
    combine_kernel<<<(NT*(DIM/8))/256, 256, 0, stream>>>(ybuf, out);
}